// Round 21
// baseline (507.233 us; speedup 1.0000x reference)
//
#include <hip/hip_runtime.h>
#include <hip/hip_bf16.h>

// Problem constants: D=1024, N=4096, K=16, M = N*K = 65536, K-dim main = 2048

typedef __attribute__((ext_vector_type(4))) float f32x4;
typedef __attribute__((ext_vector_type(2))) float f32x2;
typedef __attribute__((ext_vector_type(8))) short bf16x8;

__device__ __forceinline__ ushort f2bf(float f) {
  unsigned b = __builtin_bit_cast(unsigned, f);
  b += 0x7FFFu + ((b >> 16) & 1u);   // RNE
  return (ushort)(b >> 16);
}
__device__ __forceinline__ unsigned pk2(float a, float b) {
  return (unsigned)f2bf(a) | ((unsigned)f2bf(b) << 16);
}

// In-tile XOR swizzle for 4KB [64 rows][64B] A tiles (R16/R19-verified)
__device__ __forceinline__ unsigned swz(unsigned a) {
  return a ^ (((a >> 7) & 3u) << 4);
}

// ---------------------------------------------------------------------------
// prep: LDS tile-transpose weight packer (verified green R4-R20) + mode 3
// token f32 -> bf16 (RNE, bit-identical to per-load cvt).
// ---------------------------------------------------------------------------
__global__ __launch_bounds__(256) void prep_kernel(
    const float* __restrict__ Wl, const float* __restrict__ Wg,
    const float* __restrict__ token,
    ushort* __restrict__ Bmain, ushort* __restrict__ Bk1,
    ushort* __restrict__ Bgate, ushort* __restrict__ tokenb) {
  int t = threadIdx.x;
  int bid = blockIdx.x;
  if (bid >= 1280) {                    // mode 3: token -> bf16
    size_t base = (size_t)(bid - 1280) * 16384;
#pragma unroll
    for (int it = 0; it < 16; ++it) {
      size_t e = base + (size_t)it * 1024 + t * 4;
      f32x4 v = *(const f32x4*)(token + e);
      uint2 o; o.x = pk2(v[0], v[1]); o.y = pk2(v[2], v[3]);
      *(uint2*)(tokenb + e) = o;
    }
    return;
  }
  __shared__ float L[32][129];
  const float* src; int row0, mode, kt, wg; ushort* dst;
  if (bid < 512)      { mode = 0; kt = bid >> 3;        wg = bid & 7; src = Wl; row0 = 1024 + kt * 32; dst = Bmain; }
  else if (bid < 768) { mode = 1; kt = (bid - 512) >> 3; wg = (bid - 512) & 7; src = Wl; row0 = kt * 32; dst = Bk1; }
  else                { mode = 2; kt = (bid - 768) >> 3; wg = (bid - 768) & 7; src = Wg; row0 = kt * 32; dst = Bgate; }
  int col0 = wg * 128;
  bool dosum = (mode == 2) && (kt >= 32);
#pragma unroll
  for (int p = 0; p < 4; ++p) {
    int r = p * 8 + (t >> 5), c = (t & 31) * 4;
    const float* sp = src + (size_t)(row0 + r) * 1024 + col0 + c;
    f32x4 v = *(const f32x4*)sp;
    if (dosum) { f32x4 v2 = *(const f32x4*)(sp + (size_t)1024 * 1024); v += v2; }
    L[r][c] = v[0]; L[r][c + 1] = v[1]; L[r][c + 2] = v[2]; L[r][c + 3] = v[3];
  }
  __syncthreads();
  if (mode == 0) {
    for (int c = t; c < 512; c += 256) {
      int nf = c >> 6, lane = c & 63, lr_ = lane & 15, lh_ = lane >> 4;
      bf16x8 o;
#pragma unroll
      for (int m = 0; m < 8; ++m) o[m] = (short)f2bf(L[lh_ * 8 + m][nf * 16 + lr_]);
      *(bf16x8*)(dst + (size_t)kt * 32768 + wg * 4096 + c * 8) = o;
    }
  } else {
    for (int c = t; c < 512; c += 256) {
      int nn = c >> 2, q = c & 3;
      bf16x8 o;
#pragma unroll
      for (int m = 0; m < 8; ++m) o[m] = (short)f2bf(L[q * 8 + m][nn]);
      *(bf16x8*)(dst + (size_t)kt * 32768 + (size_t)(wg * 128 + nn) * 32 + q * 8) = o;
    }
  }
}

// ---------------------------------------------------------------------------
// gemm_small_b v2: C = act(A_bf16 @ Bpack + bias). 32x128 tile, 4 waves
// (2 row-groups x 2 col-groups), wave tile 16x64, acc[4]=16 AGPR.
// grid (M/32, 8) = 1024 blocks -> 4 blocks/CU (was 2) for TLP, and the
// K-loop uses main's proven 2-step register-double-buffered prefetch
// (named even/odd operands, 1 step ahead) instead of the old serial
// load->MFMA chain. Tail prefetch index clamped (no over-read past argb).
// Numerics bit-identical to R16-R20. NT output stores (R20).
// ---------------------------------------------------------------------------
template <int NKT, int NSPLIT, int ACT>
__global__ __launch_bounds__(256) void gemm_small_b(
    const ushort* __restrict__ A0, const ushort* __restrict__ A1,
    const ushort* __restrict__ Bp, const float* __restrict__ bias,
    float* __restrict__ Cout) {
  int tid = threadIdx.x, l = tid & 63, wid = tid >> 6;
  int wm = wid & 1, wn = wid >> 1;
  int mbase = blockIdx.x * 32 + wm * 16;
  int nbase = blockIdx.y * 128 + wn * 64;
  int lr = l & 15, lh = l >> 4;
  const size_t arow = (size_t)(mbase + lr) * 1024 + lh * 8;
  const size_t brow = (size_t)(nbase + lr) * 32 + lh * 8;   // +nf*16*32 per frag

#define LDA_(KT, DST) do {                                              \
    int k_ = (KT);                                                      \
    const ushort* As_ = (k_ < NSPLIT) ? A0 : A1;                        \
    int kb_ = (k_ < NSPLIT) ? k_ : (k_ - NSPLIT);                       \
    DST = *(const bf16x8*)(As_ + arow + kb_ * 32);                      \
  } while (0)
#define LDB_(KT, DST) do {                                              \
    const ushort* bp_ = Bp + (size_t)(KT) * 32768 + brow;               \
    _Pragma("unroll")                                                   \
    for (int nf = 0; nf < 4; ++nf)                                      \
      DST[nf] = *(const bf16x8*)(bp_ + nf * 512);                       \
  } while (0)
#define MF_(AF, BF) do {                                                \
    _Pragma("unroll")                                                   \
    for (int nf = 0; nf < 4; ++nf)                                      \
      acc[nf] = __builtin_amdgcn_mfma_f32_16x16x32_bf16(                \
          (AF), (BF)[nf], acc[nf], 0, 0, 0);                            \
  } while (0)

  f32x4 acc[4] = {};
  bf16x8 afA, afB, bfA[4], bfB[4];
  LDA_(0, afA); LDB_(0, bfA);
#pragma unroll 1
  for (int kt = 0; kt < NKT; kt += 2) {
    LDA_(kt + 1, afB); LDB_(kt + 1, bfB);      // kt+1 < NKT (NKT even)
    MF_(afA, bfA);
    int k2 = (kt + 2 < NKT) ? kt + 2 : kt;     // clamped tail (no over-read)
    LDA_(k2, afA); LDB_(k2, bfA);
    MF_(afB, bfB);
  }
#undef LDA_
#undef LDB_
#undef MF_

#pragma unroll
  for (int nf = 0; nf < 4; ++nf) {
    int col = nbase + nf * 16 + lr;
    float bs = bias[col];
#pragma unroll
    for (int j = 0; j < 4; ++j) {
      int row = mbase + lh * 4 + j;
      float v = acc[nf][j] + bs;
      if (ACT == 1) v = 1.0f / (1.0f + expf(-v));
      __builtin_nontemporal_store(v, &Cout[(size_t)row * 1024 + col]);
    }
  }
}

// ---------------------------------------------------------------------------
// main fused kernel — FROZEN green R20: barrier-free K-loop, 32 per-kt 4KB
// A tiles (in-tile swizzle), reg-dbuf B 1 ahead, s_setprio(1) around MFMA
// clusters, NT loads on read-once A/tpart, NT store on out_arg.
// ---------------------------------------------------------------------------
#define STAGE_HALF(SRC) do {                                               \
  const float* sr_ = (SRC) + (size_t)(bx * 64 + arow) * 1024 + acol * 8;   \
  _Pragma("unroll 4")                                                      \
  for (int j = 0; j < 8; ++j) {                                            \
    f32x4 va_ = __builtin_nontemporal_load((const f32x4*)(sr_ + j * 128)); \
    f32x4 vb_ = __builtin_nontemporal_load((const f32x4*)(sr_ + j * 128 + 4)); \
    uint4 o_;                                                              \
    o_.x = pk2(va_[0], va_[1]); o_.y = pk2(va_[2], va_[3]);                \
    o_.z = pk2(vb_[0], vb_[1]); o_.w = pk2(vb_[2], vb_[3]);                \
    int kt_ = j * 4 + (acol >> 2);                                         \
    unsigned ib_ = swz((unsigned)(arow * 64 + (acol & 3) * 16));           \
    *(uint4*)(smem + kt_ * 4096 + ib_) = o_;                               \
  }                                                                        \
} while (0)

#define HALF_LOOP(KT0) do {                                                \
  const ushort* bp_ = Bmain + (size_t)(KT0) * 32768 + boff;                \
  bf16x8 bfA_[4], bfB_[4];                                                 \
  _Pragma("unroll")                                                        \
  for (int nf = 0; nf < 4; ++nf)                                           \
    bfA_[nf] = *(const bf16x8*)(bp_ + nf * 512);                           \
  _Pragma("unroll 1")                                                      \
  for (int kt = 0; kt < 32; kt += 2) {                                     \
    _Pragma("unroll")                                                      \
    for (int nf = 0; nf < 4; ++nf)                                         \
      bfB_[nf] = *(const bf16x8*)(bp_ + (size_t)(kt + 1) * 32768 + nf * 512); \
    {                                                                      \
      const char* ab_ = abase + (unsigned)(kt << 12);                      \
      bf16x8 af_[4];                                                       \
      _Pragma("unroll")                                                    \
      for (int mf = 0; mf < 4; ++mf)                                       \
        af_[mf] = *(const bf16x8*)(ab_ + mf * 1024);                       \
      __builtin_amdgcn_s_setprio(1);                                       \
      _Pragma("unroll")                                                    \
      for (int nf = 0; nf < 4; ++nf)                                       \
        _Pragma("unroll")                                                  \
        for (int mf = 0; mf < 4; ++mf)                                     \
          acc[mf][nf] = __builtin_amdgcn_mfma_f32_16x16x32_bf16(           \
              af_[mf], bfA_[nf], acc[mf][nf], 0, 0, 0);                    \
      __builtin_amdgcn_s_setprio(0);                                       \
    }                                                                      \
    _Pragma("unroll")                                                      \
    for (int nf = 0; nf < 4; ++nf)  /* kt=30: over-read -> Bk1, benign */  \
      bfA_[nf] = *(const bf16x8*)(bp_ + (size_t)(kt + 2) * 32768 + nf * 512); \
    {                                                                      \
      const char* ab_ = abase + (unsigned)((kt + 1) << 12);                \
      bf16x8 af_[4];                                                       \
      _Pragma("unroll")                                                    \
      for (int mf = 0; mf < 4; ++mf)                                       \
        af_[mf] = *(const bf16x8*)(ab_ + mf * 1024);                       \
      __builtin_amdgcn_s_setprio(1);                                       \
      _Pragma("unroll")                                                    \
      for (int nf = 0; nf < 4; ++nf)                                       \
        _Pragma("unroll")                                                  \
        for (int mf = 0; mf < 4; ++mf)                                     \
          acc[mf][nf] = __builtin_amdgcn_mfma_f32_16x16x32_bf16(           \
              af_[mf], bfB_[nf], acc[mf][nf], 0, 0, 0);                    \
      __builtin_amdgcn_s_setprio(0);                                       \
    }                                                                      \
  }                                                                        \
} while (0)

__global__ __launch_bounds__(1024) void main_kernel(
    const float* __restrict__ routed, const float* __restrict__ delta,
    const float* __restrict__ simrow, const ushort* __restrict__ Bmain,
    const float* __restrict__ tpart, const float* __restrict__ gamma,
    const float* __restrict__ beta, float* __restrict__ out_arg,
    ushort* __restrict__ argb) {
  extern __shared__ char smem[];
  float* ldsW = (float*)(smem + 131072);
  float* lnS = (float*)smem;
  float* lnQ = (float*)(smem + 4096);

  int tid = threadIdx.x, l = tid & 63, wid = tid >> 6;   // wid 0..15
  int bx = blockIdx.x;                  // tokens bx*4 .. bx*4+3
  int lr = l & 15, lh = l >> 4;

  if (tid < 4) {                        // softmax over K=16 for token bx*4+tid
    int n = bx * 4 + tid;
    float sv[16], mx = -1e30f;
#pragma unroll
    for (int j = 0; j < 16; ++j) { sv[j] = simrow[n * 16 + j]; mx = fmaxf(mx, sv[j]); }
    float s = 0.f;
#pragma unroll
    for (int j = 0; j < 16; ++j) { sv[j] = expf(sv[j] - mx); s += sv[j]; }
    float inv = 1.0f / s;
#pragma unroll
    for (int j = 0; j < 16; ++j) ldsW[tid * 16 + j] = sv[j] * inv;
  }

  const int arow = tid >> 4;            // 0..63
  const int acol = tid & 15;            // 0..15

  const unsigned aoff0 = swz((unsigned)(lr * 64 + lh * 16));
  const char* abase = smem + aoff0;

  const size_t boff = (size_t)(wid >> 1) * 4096 + (size_t)(wid & 1) * 2048 +
                      (size_t)l * 8;

  f32x4 acc[4][4] = {};

  STAGE_HALF(routed);
  __syncthreads();
  HALF_LOOP(0);
  __syncthreads();
  STAGE_HALF(delta);
  __syncthreads();
  HALF_LOOP(32);
  __syncthreads();

  // ---- fused epilogue (green R16-R20; fast GELU, tpart NT) ----
  const float inv_d = 1.0f / 1024.0f;
  float gam[4], bet[4];
#pragma unroll
  for (int nf = 0; nf < 4; ++nf) {
    int c = wid * 64 + nf * 16 + lr;
    gam[nf] = gamma[c]; bet[nf] = beta[c];
  }
#pragma unroll
  for (int mf = 0; mf < 4; ++mf) {
    int tokrow = bx * 4 + mf;
    float s[4] = {0, 0, 0, 0}, q[4] = {0, 0, 0, 0};
#pragma unroll
    for (int nf = 0; nf < 4; ++nf) {
      float tp = __builtin_nontemporal_load(
          tpart + (size_t)tokrow * 1024 + wid * 64 + nf * 16 + lr);
#pragma unroll
      for (int j = 0; j < 4; ++j) {
        float h = acc[mf][nf][j] + tp;
        float u = h * (1.5957691f + 0.07135481f * h * h);
        float g = h / (1.0f + __expf(-u));
        acc[mf][nf][j] = g;
        s[j] += g; q[j] += g * g;
      }
    }
#pragma unroll
    for (int j = 0; j < 4; ++j) {
#pragma unroll
      for (int d = 1; d <= 8; d <<= 1) {
        s[j] += __shfl_xor(s[j], d, 64);
        q[j] += __shfl_xor(q[j], d, 64);
      }
    }
    if (lr == 0) {
#pragma unroll
      for (int j = 0; j < 4; ++j) {
        int row = mf * 16 + lh * 4 + j;
        lnS[row * 16 + wid] = s[j];
        lnQ[row * 16 + wid] = q[j];
      }
    }
  }
  __syncthreads();
#pragma unroll
  for (int mf = 0; mf < 4; ++mf) {
    float mu[4], rs[4], wk[4];
#pragma unroll
    for (int j = 0; j < 4; ++j) {
      int row = mf * 16 + lh * 4 + j;
      float S = 0.f, Q = 0.f;
#pragma unroll
      for (int w4 = 0; w4 < 4; ++w4) {
        f32x4 vs = *(const f32x4*)&lnS[row * 16 + w4 * 4];
        f32x4 vq = *(const f32x4*)&lnQ[row * 16 + w4 * 4];
        S += vs[0] + vs[1] + vs[2] + vs[3];
        Q += vq[0] + vq[1] + vq[2] + vq[3];
      }
      float m_ = S * inv_d;
      mu[j] = m_;
      rs[j] = rsqrtf(Q * inv_d - m_ * m_ + 1e-5f);
      wk[j] = ldsW[row];
    }
#pragma unroll
    for (int nf = 0; nf < 4; ++nf) {
      float ws = 0.f;
#pragma unroll
      for (int j = 0; j < 4; ++j) {
        float y = (acc[mf][nf][j] - mu[j]) * rs[j] * gam[nf] + bet[nf];
        ws += wk[j] * y;
      }
      ws += __shfl_xor(ws, 16, 64);
      ws += __shfl_xor(ws, 32, 64);
      if (lh == 0) {
        size_t oidx = (size_t)(bx * 4 + mf) * 1024 + wid * 64 + nf * 16 + lr;
        __builtin_nontemporal_store(ws, &out_arg[oidx]);   // never re-read
        argb[oidx] = f2bf(ws);                             // re-read 8x: cached
      }
    }
  }
}

// ---------------------------------------------------------------------------
extern "C" void kernel_launch(void* const* d_in, const int* in_sizes, int n_in,
                              void* d_out, int out_size, void* d_ws, size_t ws_size,
                              hipStream_t stream) {
  const float* token  = (const float*)d_in[0];
  const float* routed = (const float*)d_in[1];
  const float* simrow = (const float*)d_in[2];
  const float* delta  = (const float*)d_in[3];
  const float* Wl     = (const float*)d_in[4];
  const float* bl     = (const float*)d_in[5];
  const float* gamma  = (const float*)d_in[6];
  const float* beta   = (const float*)d_in[7];
  const float* Wg     = (const float*)d_in[8];
  const float* bg     = (const float*)d_in[9];

  char* ws = (char*)d_ws;
  ushort* Bmain  = (ushort*)(ws);                        // 4 MB
  ushort* Bk1    = (ushort*)(ws + (4u << 20));           // 2 MB
  ushort* Bgate  = (ushort*)(ws + (6u << 20));           // 4 MB
  float*  tpart  = (float*)(ws + (10u << 20));           // 16 MB
  ushort* tokenb = (ushort*)(ws + (26u << 20));          // 8 MB
  ushort* argb   = (ushort*)(ws + (34u << 20));          // 8 MB (total 42 MB)

  float* out_arg  = (float*)d_out;
  float* out_gate = out_arg + (size_t)4096 * 1024;

  const int SMEM = 131328;   // 32 A tiles 128K | ldsW 256B
  hipFuncSetAttribute(reinterpret_cast<const void*>(main_kernel),
                      hipFuncAttributeMaxDynamicSharedMemorySize, SMEM);

  prep_kernel<<<1536, 256, 0, stream>>>(Wl, Wg, token, Bmain, Bk1, Bgate, tokenb);
  gemm_small_b<32, 32, 0><<<dim3(128, 8), 256, 0, stream>>>(
      tokenb, tokenb, Bk1, bl, tpart);
  main_kernel<<<1024, 1024, SMEM, stream>>>(
      routed, delta, simrow, Bmain, tpart, gamma, beta, out_arg, argb);
  gemm_small_b<64, 32, 1><<<dim3(128, 8), 256, 0, stream>>>(
      tokenb, argb, Bgate, bg, out_gate);
}

// Round 22
// 471.398 us; speedup vs baseline: 1.0760x; 1.0760x over previous
//
#include <hip/hip_runtime.h>
#include <hip/hip_bf16.h>

// Problem constants: D=1024, N=4096, K=16, M = N*K = 65536, K-dim main = 2048

typedef __attribute__((ext_vector_type(4))) float f32x4;
typedef __attribute__((ext_vector_type(2))) float f32x2;
typedef __attribute__((ext_vector_type(8))) short bf16x8;

__device__ __forceinline__ ushort f2bf(float f) {
  unsigned b = __builtin_bit_cast(unsigned, f);
  b += 0x7FFFu + ((b >> 16) & 1u);   // RNE
  return (ushort)(b >> 16);
}
__device__ __forceinline__ unsigned pk2(float a, float b) {
  return (unsigned)f2bf(a) | ((unsigned)f2bf(b) << 16);
}

// In-tile XOR swizzle for 4KB [64 rows][64B] A tiles (R16/R19-verified)
__device__ __forceinline__ unsigned swz(unsigned a) {
  return a ^ (((a >> 7) & 3u) << 4);
}

// ---------------------------------------------------------------------------
// prep: LDS tile-transpose weight packer (verified green R4-R21) + mode 3
// token f32 -> bf16 (RNE, bit-identical to per-load cvt).
// ---------------------------------------------------------------------------
__global__ __launch_bounds__(256) void prep_kernel(
    const float* __restrict__ Wl, const float* __restrict__ Wg,
    const float* __restrict__ token,
    ushort* __restrict__ Bmain, ushort* __restrict__ Bk1,
    ushort* __restrict__ Bgate, ushort* __restrict__ tokenb) {
  int t = threadIdx.x;
  int bid = blockIdx.x;
  if (bid >= 1280) {                    // mode 3: token -> bf16
    size_t base = (size_t)(bid - 1280) * 16384;
#pragma unroll
    for (int it = 0; it < 16; ++it) {
      size_t e = base + (size_t)it * 1024 + t * 4;
      f32x4 v = *(const f32x4*)(token + e);
      uint2 o; o.x = pk2(v[0], v[1]); o.y = pk2(v[2], v[3]);
      *(uint2*)(tokenb + e) = o;
    }
    return;
  }
  __shared__ float L[32][129];
  const float* src; int row0, mode, kt, wg; ushort* dst;
  if (bid < 512)      { mode = 0; kt = bid >> 3;        wg = bid & 7; src = Wl; row0 = 1024 + kt * 32; dst = Bmain; }
  else if (bid < 768) { mode = 1; kt = (bid - 512) >> 3; wg = (bid - 512) & 7; src = Wl; row0 = kt * 32; dst = Bk1; }
  else                { mode = 2; kt = (bid - 768) >> 3; wg = (bid - 768) & 7; src = Wg; row0 = kt * 32; dst = Bgate; }
  int col0 = wg * 128;
  bool dosum = (mode == 2) && (kt >= 32);
#pragma unroll
  for (int p = 0; p < 4; ++p) {
    int r = p * 8 + (t >> 5), c = (t & 31) * 4;
    const float* sp = src + (size_t)(row0 + r) * 1024 + col0 + c;
    f32x4 v = *(const f32x4*)sp;
    if (dosum) { f32x4 v2 = *(const f32x4*)(sp + (size_t)1024 * 1024); v += v2; }
    L[r][c] = v[0]; L[r][c + 1] = v[1]; L[r][c + 2] = v[2]; L[r][c + 3] = v[3];
  }
  __syncthreads();
  if (mode == 0) {
    for (int c = t; c < 512; c += 256) {
      int nf = c >> 6, lane = c & 63, lr_ = lane & 15, lh_ = lane >> 4;
      bf16x8 o;
#pragma unroll
      for (int m = 0; m < 8; ++m) o[m] = (short)f2bf(L[lh_ * 8 + m][nf * 16 + lr_]);
      *(bf16x8*)(dst + (size_t)kt * 32768 + wg * 4096 + c * 8) = o;
    }
  } else {
    for (int c = t; c < 512; c += 256) {
      int nn = c >> 2, q = c & 3;
      bf16x8 o;
#pragma unroll
      for (int m = 0; m < 8; ++m) o[m] = (short)f2bf(L[q * 8 + m][nn]);
      *(bf16x8*)(dst + (size_t)kt * 32768 + (size_t)(wg * 128 + nn) * 32 + q * 8) = o;
    }
  }
}

// ---------------------------------------------------------------------------
// gemm_small_b: C = act(A_bf16 @ Bpack + bias). EXACT green R20 version:
// 64x128 tile, 4 waves (2x2), wave tile 32x64, grid (M/64, 8) = 512 blocks.
// (R21's 32-row variant doubled per-panel B L2 traffic -> +37us; reverted.)
// NT output stores (R20): tpart/out_gate streams don't evict hot B panels.
// ---------------------------------------------------------------------------
template <int NKT, int NSPLIT, int ACT>
__global__ __launch_bounds__(256) void gemm_small_b(
    const ushort* __restrict__ A0, const ushort* __restrict__ A1,
    const ushort* __restrict__ Bp, const float* __restrict__ bias,
    float* __restrict__ Cout) {
  int tid = threadIdx.x, l = tid & 63, wid = tid >> 6;
  int wm = wid & 1, wn = wid >> 1;
  int mbase = blockIdx.x * 64 + wm * 32;
  int nbase = blockIdx.y * 128 + wn * 64;
  int lr = l & 15, lh = l >> 4;
  f32x4 acc[2][4] = {};
#pragma unroll 1
  for (int kt = 0; kt < NKT; ++kt) {
    const ushort* As = (kt < NSPLIT) ? A0 : A1;
    int ke = ((kt < NSPLIT) ? kt : kt - NSPLIT) * 32 + lh * 8;
    bf16x8 af[2];
#pragma unroll
    for (int mf = 0; mf < 2; ++mf)
      af[mf] = *(const bf16x8*)(As + (size_t)(mbase + mf * 16 + lr) * 1024 + ke);
    bf16x8 bf[4];
#pragma unroll
    for (int nf = 0; nf < 4; ++nf)
      bf[nf] = *(const bf16x8*)(Bp + (size_t)kt * 32768 +
                                (size_t)(nbase + nf * 16 + lr) * 32 + lh * 8);
#pragma unroll
    for (int nf = 0; nf < 4; ++nf)
#pragma unroll
      for (int mf = 0; mf < 2; ++mf)
        acc[mf][nf] = __builtin_amdgcn_mfma_f32_16x16x32_bf16(
            af[mf], bf[nf], acc[mf][nf], 0, 0, 0);
  }
#pragma unroll
  for (int nf = 0; nf < 4; ++nf) {
    int col = nbase + nf * 16 + lr;
    float bs = bias[col];
#pragma unroll
    for (int mf = 0; mf < 2; ++mf)
#pragma unroll
      for (int j = 0; j < 4; ++j) {
        int row = mbase + mf * 16 + lh * 4 + j;
        float v = acc[mf][nf][j] + bs;
        if (ACT == 1) v = 1.0f / (1.0f + expf(-v));
        __builtin_nontemporal_store(v, &Cout[(size_t)row * 1024 + col]);
      }
  }
}

// ---------------------------------------------------------------------------
// main fused kernel — FROZEN green R20: barrier-free K-loop, 32 per-kt 4KB
// A tiles (in-tile swizzle), reg-dbuf B 1 ahead, s_setprio(1) around MFMA
// clusters, NT loads on read-once A/tpart, NT store on out_arg.
// ---------------------------------------------------------------------------
#define STAGE_HALF(SRC) do {                                               \
  const float* sr_ = (SRC) + (size_t)(bx * 64 + arow) * 1024 + acol * 8;   \
  _Pragma("unroll 4")                                                      \
  for (int j = 0; j < 8; ++j) {                                            \
    f32x4 va_ = __builtin_nontemporal_load((const f32x4*)(sr_ + j * 128)); \
    f32x4 vb_ = __builtin_nontemporal_load((const f32x4*)(sr_ + j * 128 + 4)); \
    uint4 o_;                                                              \
    o_.x = pk2(va_[0], va_[1]); o_.y = pk2(va_[2], va_[3]);                \
    o_.z = pk2(vb_[0], vb_[1]); o_.w = pk2(vb_[2], vb_[3]);                \
    int kt_ = j * 4 + (acol >> 2);                                         \
    unsigned ib_ = swz((unsigned)(arow * 64 + (acol & 3) * 16));           \
    *(uint4*)(smem + kt_ * 4096 + ib_) = o_;                               \
  }                                                                        \
} while (0)

#define HALF_LOOP(KT0) do {                                                \
  const ushort* bp_ = Bmain + (size_t)(KT0) * 32768 + boff;                \
  bf16x8 bfA_[4], bfB_[4];                                                 \
  _Pragma("unroll")                                                        \
  for (int nf = 0; nf < 4; ++nf)                                           \
    bfA_[nf] = *(const bf16x8*)(bp_ + nf * 512);                           \
  _Pragma("unroll 1")                                                      \
  for (int kt = 0; kt < 32; kt += 2) {                                     \
    _Pragma("unroll")                                                      \
    for (int nf = 0; nf < 4; ++nf)                                         \
      bfB_[nf] = *(const bf16x8*)(bp_ + (size_t)(kt + 1) * 32768 + nf * 512); \
    {                                                                      \
      const char* ab_ = abase + (unsigned)(kt << 12);                      \
      bf16x8 af_[4];                                                       \
      _Pragma("unroll")                                                    \
      for (int mf = 0; mf < 4; ++mf)                                       \
        af_[mf] = *(const bf16x8*)(ab_ + mf * 1024);                       \
      __builtin_amdgcn_s_setprio(1);                                       \
      _Pragma("unroll")                                                    \
      for (int nf = 0; nf < 4; ++nf)                                       \
        _Pragma("unroll")                                                  \
        for (int mf = 0; mf < 4; ++mf)                                     \
          acc[mf][nf] = __builtin_amdgcn_mfma_f32_16x16x32_bf16(           \
              af_[mf], bfA_[nf], acc[mf][nf], 0, 0, 0);                    \
      __builtin_amdgcn_s_setprio(0);                                       \
    }                                                                      \
    _Pragma("unroll")                                                      \
    for (int nf = 0; nf < 4; ++nf)  /* kt=30: over-read -> Bk1, benign */  \
      bfA_[nf] = *(const bf16x8*)(bp_ + (size_t)(kt + 2) * 32768 + nf * 512); \
    {                                                                      \
      const char* ab_ = abase + (unsigned)((kt + 1) << 12);                \
      bf16x8 af_[4];                                                       \
      _Pragma("unroll")                                                    \
      for (int mf = 0; mf < 4; ++mf)                                       \
        af_[mf] = *(const bf16x8*)(ab_ + mf * 1024);                       \
      __builtin_amdgcn_s_setprio(1);                                       \
      _Pragma("unroll")                                                    \
      for (int nf = 0; nf < 4; ++nf)                                       \
        _Pragma("unroll")                                                  \
        for (int mf = 0; mf < 4; ++mf)                                     \
          acc[mf][nf] = __builtin_amdgcn_mfma_f32_16x16x32_bf16(           \
              af_[mf], bfB_[nf], acc[mf][nf], 0, 0, 0);                    \
      __builtin_amdgcn_s_setprio(0);                                       \
    }                                                                      \
  }                                                                        \
} while (0)

__global__ __launch_bounds__(1024) void main_kernel(
    const float* __restrict__ routed, const float* __restrict__ delta,
    const float* __restrict__ simrow, const ushort* __restrict__ Bmain,
    const float* __restrict__ tpart, const float* __restrict__ gamma,
    const float* __restrict__ beta, float* __restrict__ out_arg,
    ushort* __restrict__ argb) {
  extern __shared__ char smem[];
  float* ldsW = (float*)(smem + 131072);
  float* lnS = (float*)smem;
  float* lnQ = (float*)(smem + 4096);

  int tid = threadIdx.x, l = tid & 63, wid = tid >> 6;   // wid 0..15
  int bx = blockIdx.x;                  // tokens bx*4 .. bx*4+3
  int lr = l & 15, lh = l >> 4;

  if (tid < 4) {                        // softmax over K=16 for token bx*4+tid
    int n = bx * 4 + tid;
    float sv[16], mx = -1e30f;
#pragma unroll
    for (int j = 0; j < 16; ++j) { sv[j] = simrow[n * 16 + j]; mx = fmaxf(mx, sv[j]); }
    float s = 0.f;
#pragma unroll
    for (int j = 0; j < 16; ++j) { sv[j] = expf(sv[j] - mx); s += sv[j]; }
    float inv = 1.0f / s;
#pragma unroll
    for (int j = 0; j < 16; ++j) ldsW[tid * 16 + j] = sv[j] * inv;
  }

  const int arow = tid >> 4;            // 0..63
  const int acol = tid & 15;            // 0..15

  const unsigned aoff0 = swz((unsigned)(lr * 64 + lh * 16));
  const char* abase = smem + aoff0;

  const size_t boff = (size_t)(wid >> 1) * 4096 + (size_t)(wid & 1) * 2048 +
                      (size_t)l * 8;

  f32x4 acc[4][4] = {};

  STAGE_HALF(routed);
  __syncthreads();
  HALF_LOOP(0);
  __syncthreads();
  STAGE_HALF(delta);
  __syncthreads();
  HALF_LOOP(32);
  __syncthreads();

  // ---- fused epilogue (green R16-R20; fast GELU, tpart NT) ----
  const float inv_d = 1.0f / 1024.0f;
  float gam[4], bet[4];
#pragma unroll
  for (int nf = 0; nf < 4; ++nf) {
    int c = wid * 64 + nf * 16 + lr;
    gam[nf] = gamma[c]; bet[nf] = beta[c];
  }
#pragma unroll
  for (int mf = 0; mf < 4; ++mf) {
    int tokrow = bx * 4 + mf;
    float s[4] = {0, 0, 0, 0}, q[4] = {0, 0, 0, 0};
#pragma unroll
    for (int nf = 0; nf < 4; ++nf) {
      float tp = __builtin_nontemporal_load(
          tpart + (size_t)tokrow * 1024 + wid * 64 + nf * 16 + lr);
#pragma unroll
      for (int j = 0; j < 4; ++j) {
        float h = acc[mf][nf][j] + tp;
        float u = h * (1.5957691f + 0.07135481f * h * h);
        float g = h / (1.0f + __expf(-u));
        acc[mf][nf][j] = g;
        s[j] += g; q[j] += g * g;
      }
    }
#pragma unroll
    for (int j = 0; j < 4; ++j) {
#pragma unroll
      for (int d = 1; d <= 8; d <<= 1) {
        s[j] += __shfl_xor(s[j], d, 64);
        q[j] += __shfl_xor(q[j], d, 64);
      }
    }
    if (lr == 0) {
#pragma unroll
      for (int j = 0; j < 4; ++j) {
        int row = mf * 16 + lh * 4 + j;
        lnS[row * 16 + wid] = s[j];
        lnQ[row * 16 + wid] = q[j];
      }
    }
  }
  __syncthreads();
#pragma unroll
  for (int mf = 0; mf < 4; ++mf) {
    float mu[4], rs[4], wk[4];
#pragma unroll
    for (int j = 0; j < 4; ++j) {
      int row = mf * 16 + lh * 4 + j;
      float S = 0.f, Q = 0.f;
#pragma unroll
      for (int w4 = 0; w4 < 4; ++w4) {
        f32x4 vs = *(const f32x4*)&lnS[row * 16 + w4 * 4];
        f32x4 vq = *(const f32x4*)&lnQ[row * 16 + w4 * 4];
        S += vs[0] + vs[1] + vs[2] + vs[3];
        Q += vq[0] + vq[1] + vq[2] + vq[3];
      }
      float m_ = S * inv_d;
      mu[j] = m_;
      rs[j] = rsqrtf(Q * inv_d - m_ * m_ + 1e-5f);
      wk[j] = ldsW[row];
    }
#pragma unroll
    for (int nf = 0; nf < 4; ++nf) {
      float ws = 0.f;
#pragma unroll
      for (int j = 0; j < 4; ++j) {
        float y = (acc[mf][nf][j] - mu[j]) * rs[j] * gam[nf] + bet[nf];
        ws += wk[j] * y;
      }
      ws += __shfl_xor(ws, 16, 64);
      ws += __shfl_xor(ws, 32, 64);
      if (lh == 0) {
        size_t oidx = (size_t)(bx * 4 + mf) * 1024 + wid * 64 + nf * 16 + lr;
        __builtin_nontemporal_store(ws, &out_arg[oidx]);   // never re-read
        argb[oidx] = f2bf(ws);                             // re-read 8x: cached
      }
    }
  }
}

// ---------------------------------------------------------------------------
extern "C" void kernel_launch(void* const* d_in, const int* in_sizes, int n_in,
                              void* d_out, int out_size, void* d_ws, size_t ws_size,
                              hipStream_t stream) {
  const float* token  = (const float*)d_in[0];
  const float* routed = (const float*)d_in[1];
  const float* simrow = (const float*)d_in[2];
  const float* delta  = (const float*)d_in[3];
  const float* Wl     = (const float*)d_in[4];
  const float* bl     = (const float*)d_in[5];
  const float* gamma  = (const float*)d_in[6];
  const float* beta   = (const float*)d_in[7];
  const float* Wg     = (const float*)d_in[8];
  const float* bg     = (const float*)d_in[9];

  char* ws = (char*)d_ws;
  ushort* Bmain  = (ushort*)(ws);                        // 4 MB
  ushort* Bk1    = (ushort*)(ws + (4u << 20));           // 2 MB
  ushort* Bgate  = (ushort*)(ws + (6u << 20));           // 4 MB
  float*  tpart  = (float*)(ws + (10u << 20));           // 16 MB
  ushort* tokenb = (ushort*)(ws + (26u << 20));          // 8 MB
  ushort* argb   = (ushort*)(ws + (34u << 20));          // 8 MB (total 42 MB)

  float* out_arg  = (float*)d_out;
  float* out_gate = out_arg + (size_t)4096 * 1024;

  const int SMEM = 131328;   // 32 A tiles 128K | ldsW 256B
  hipFuncSetAttribute(reinterpret_cast<const void*>(main_kernel),
                      hipFuncAttributeMaxDynamicSharedMemorySize, SMEM);

  prep_kernel<<<1536, 256, 0, stream>>>(Wl, Wg, token, Bmain, Bk1, Bgate, tokenb);
  gemm_small_b<32, 32, 0><<<dim3(64, 8), 256, 0, stream>>>(
      tokenb, tokenb, Bk1, bl, tpart);
  main_kernel<<<1024, 1024, SMEM, stream>>>(
      routed, delta, simrow, Bmain, tpart, gamma, beta, out_arg, argb);
  gemm_small_b<64, 32, 1><<<dim3(64, 8), 256, 0, stream>>>(
      tokenb, argb, Bgate, bg, out_gate);
}

// Round 23
// 470.964 us; speedup vs baseline: 1.0770x; 1.0009x over previous
//
#include <hip/hip_runtime.h>
#include <hip/hip_bf16.h>

// Problem constants: D=1024, N=4096, K=16, M = N*K = 65536, K-dim main = 2048

typedef __attribute__((ext_vector_type(4))) float f32x4;
typedef __attribute__((ext_vector_type(2))) float f32x2;
typedef __attribute__((ext_vector_type(8))) short bf16x8;

__device__ __forceinline__ ushort f2bf(float f) {
  unsigned b = __builtin_bit_cast(unsigned, f);
  b += 0x7FFFu + ((b >> 16) & 1u);   // RNE
  return (ushort)(b >> 16);
}
__device__ __forceinline__ unsigned pk2(float a, float b) {
  return (unsigned)f2bf(a) | ((unsigned)f2bf(b) << 16);
}

// In-tile XOR swizzle for 4KB [64 rows][64B] A tiles (R16/R19-verified)
__device__ __forceinline__ unsigned swz(unsigned a) {
  return a ^ (((a >> 7) & 3u) << 4);
}

// ---------------------------------------------------------------------------
// prep: LDS tile-transpose weight packer (verified green R4-R22) + mode 3
// token f32 -> bf16 (RNE, bit-identical to per-load cvt).
// ---------------------------------------------------------------------------
__global__ __launch_bounds__(256) void prep_kernel(
    const float* __restrict__ Wl, const float* __restrict__ Wg,
    const float* __restrict__ token,
    ushort* __restrict__ Bmain, ushort* __restrict__ Bk1,
    ushort* __restrict__ Bgate, ushort* __restrict__ tokenb) {
  int t = threadIdx.x;
  int bid = blockIdx.x;
  if (bid >= 1280) {                    // mode 3: token -> bf16
    size_t base = (size_t)(bid - 1280) * 16384;
#pragma unroll
    for (int it = 0; it < 16; ++it) {
      size_t e = base + (size_t)it * 1024 + t * 4;
      f32x4 v = *(const f32x4*)(token + e);
      uint2 o; o.x = pk2(v[0], v[1]); o.y = pk2(v[2], v[3]);
      *(uint2*)(tokenb + e) = o;
    }
    return;
  }
  __shared__ float L[32][129];
  const float* src; int row0, mode, kt, wg; ushort* dst;
  if (bid < 512)      { mode = 0; kt = bid >> 3;        wg = bid & 7; src = Wl; row0 = 1024 + kt * 32; dst = Bmain; }
  else if (bid < 768) { mode = 1; kt = (bid - 512) >> 3; wg = (bid - 512) & 7; src = Wl; row0 = kt * 32; dst = Bk1; }
  else                { mode = 2; kt = (bid - 768) >> 3; wg = (bid - 768) & 7; src = Wg; row0 = kt * 32; dst = Bgate; }
  int col0 = wg * 128;
  bool dosum = (mode == 2) && (kt >= 32);
#pragma unroll
  for (int p = 0; p < 4; ++p) {
    int r = p * 8 + (t >> 5), c = (t & 31) * 4;
    const float* sp = src + (size_t)(row0 + r) * 1024 + col0 + c;
    f32x4 v = *(const f32x4*)sp;
    if (dosum) { f32x4 v2 = *(const f32x4*)(sp + (size_t)1024 * 1024); v += v2; }
    L[r][c] = v[0]; L[r][c + 1] = v[1]; L[r][c + 2] = v[2]; L[r][c + 3] = v[3];
  }
  __syncthreads();
  if (mode == 0) {
    for (int c = t; c < 512; c += 256) {
      int nf = c >> 6, lane = c & 63, lr_ = lane & 15, lh_ = lane >> 4;
      bf16x8 o;
#pragma unroll
      for (int m = 0; m < 8; ++m) o[m] = (short)f2bf(L[lh_ * 8 + m][nf * 16 + lr_]);
      *(bf16x8*)(dst + (size_t)kt * 32768 + wg * 4096 + c * 8) = o;
    }
  } else {
    for (int c = t; c < 512; c += 256) {
      int nn = c >> 2, q = c & 3;
      bf16x8 o;
#pragma unroll
      for (int m = 0; m < 8; ++m) o[m] = (short)f2bf(L[q * 8 + m][nn]);
      *(bf16x8*)(dst + (size_t)kt * 32768 + (size_t)(wg * 128 + nn) * 32 + q * 8) = o;
    }
  }
}

// ---------------------------------------------------------------------------
// gemm_small_b: C = act(A_bf16 @ Bpack + bias). EXACT green R20/R22 version:
// 64x128 tile, 4 waves (2x2), wave tile 32x64, grid (M/64, 8) = 512 blocks.
// NT output stores: tpart/out_gate streams don't evict hot B panels.
// ---------------------------------------------------------------------------
template <int NKT, int NSPLIT, int ACT>
__global__ __launch_bounds__(256) void gemm_small_b(
    const ushort* __restrict__ A0, const ushort* __restrict__ A1,
    const ushort* __restrict__ Bp, const float* __restrict__ bias,
    float* __restrict__ Cout) {
  int tid = threadIdx.x, l = tid & 63, wid = tid >> 6;
  int wm = wid & 1, wn = wid >> 1;
  int mbase = blockIdx.x * 64 + wm * 32;
  int nbase = blockIdx.y * 128 + wn * 64;
  int lr = l & 15, lh = l >> 4;
  f32x4 acc[2][4] = {};
#pragma unroll 1
  for (int kt = 0; kt < NKT; ++kt) {
    const ushort* As = (kt < NSPLIT) ? A0 : A1;
    int ke = ((kt < NSPLIT) ? kt : kt - NSPLIT) * 32 + lh * 8;
    bf16x8 af[2];
#pragma unroll
    for (int mf = 0; mf < 2; ++mf)
      af[mf] = *(const bf16x8*)(As + (size_t)(mbase + mf * 16 + lr) * 1024 + ke);
    bf16x8 bf[4];
#pragma unroll
    for (int nf = 0; nf < 4; ++nf)
      bf[nf] = *(const bf16x8*)(Bp + (size_t)kt * 32768 +
                                (size_t)(nbase + nf * 16 + lr) * 32 + lh * 8);
#pragma unroll
    for (int nf = 0; nf < 4; ++nf)
#pragma unroll
      for (int mf = 0; mf < 2; ++mf)
        acc[mf][nf] = __builtin_amdgcn_mfma_f32_16x16x32_bf16(
            af[mf], bf[nf], acc[mf][nf], 0, 0, 0);
  }
#pragma unroll
  for (int nf = 0; nf < 4; ++nf) {
    int col = nbase + nf * 16 + lr;
    float bs = bias[col];
#pragma unroll
    for (int mf = 0; mf < 2; ++mf)
#pragma unroll
      for (int j = 0; j < 4; ++j) {
        int row = mbase + mf * 16 + lh * 4 + j;
        float v = acc[mf][nf][j] + bs;
        if (ACT == 1) v = 1.0f / (1.0f + expf(-v));
        __builtin_nontemporal_store(v, &Cout[(size_t)row * 1024 + col]);
      }
  }
}

// ---------------------------------------------------------------------------
// main fused kernel — green R20/R22 structure with STRENGTH-REDUCED K-loop
// ADDRESSING: running pointers bp0_/bp1_ (even/odd B tiles, +65536 ushorts
// per 2-step) and ap_ (+8192B per 2-step) replace the per-load-group
// recomputation of bp_+(kt+1)*32768 / abase+(kt<<12). Every load offset now
// folds into the instruction immediate (B: nf*1024B <= 3072; A ds_read:
// {0,4096}+mf*1024 <= 7168). Same loads, same order, same data. Targets the
// anomalous VALUBusy 36% (measured ~1280cy/step/SIMD vs <400 expected).
// ---------------------------------------------------------------------------
#define STAGE_HALF(SRC) do {                                               \
  const float* sr_ = (SRC) + (size_t)(bx * 64 + arow) * 1024 + acol * 8;   \
  _Pragma("unroll 4")                                                      \
  for (int j = 0; j < 8; ++j) {                                            \
    f32x4 va_ = __builtin_nontemporal_load((const f32x4*)(sr_ + j * 128)); \
    f32x4 vb_ = __builtin_nontemporal_load((const f32x4*)(sr_ + j * 128 + 4)); \
    uint4 o_;                                                              \
    o_.x = pk2(va_[0], va_[1]); o_.y = pk2(va_[2], va_[3]);                \
    o_.z = pk2(vb_[0], vb_[1]); o_.w = pk2(vb_[2], vb_[3]);                \
    int kt_ = j * 4 + (acol >> 2);                                         \
    unsigned ib_ = swz((unsigned)(arow * 64 + (acol & 3) * 16));           \
    *(uint4*)(smem + kt_ * 4096 + ib_) = o_;                               \
  }                                                                        \
} while (0)

#define HALF_LOOP(KT0) do {                                                \
  const ushort* bp0_ = Bmain + (size_t)(KT0) * 32768 + boff;  /* even */   \
  const ushort* bp1_ = bp0_ + 32768;                          /* odd  */   \
  const char* ap_ = abase;                                                 \
  bf16x8 bfA_[4], bfB_[4];                                                 \
  _Pragma("unroll")                                                        \
  for (int nf = 0; nf < 4; ++nf)                                           \
    bfA_[nf] = *(const bf16x8*)(bp0_ + nf * 512);             /* tile 0 */ \
  bp0_ += 65536;                                              /* tile 2 */ \
  _Pragma("unroll 1")                                                      \
  for (int kt = 0; kt < 32; kt += 2) {                                     \
    _Pragma("unroll")                                                      \
    for (int nf = 0; nf < 4; ++nf)           /* tile kt+1 */               \
      bfB_[nf] = *(const bf16x8*)(bp1_ + nf * 512);                        \
    {                                                                      \
      bf16x8 af_[4];                                                       \
      _Pragma("unroll")                                                    \
      for (int mf = 0; mf < 4; ++mf)                                       \
        af_[mf] = *(const bf16x8*)(ap_ + mf * 1024);                       \
      __builtin_amdgcn_s_setprio(1);                                       \
      _Pragma("unroll")                                                    \
      for (int nf = 0; nf < 4; ++nf)                                       \
        _Pragma("unroll")                                                  \
        for (int mf = 0; mf < 4; ++mf)                                     \
          acc[mf][nf] = __builtin_amdgcn_mfma_f32_16x16x32_bf16(           \
              af_[mf], bfA_[nf], acc[mf][nf], 0, 0, 0);                    \
      __builtin_amdgcn_s_setprio(0);                                       \
    }                                                                      \
    _Pragma("unroll")                                                      \
    for (int nf = 0; nf < 4; ++nf)  /* tile kt+2; kt=30 over-read -> Bk1 */\
      bfA_[nf] = *(const bf16x8*)(bp0_ + nf * 512);                        \
    {                                                                      \
      bf16x8 af_[4];                                                       \
      _Pragma("unroll")                                                    \
      for (int mf = 0; mf < 4; ++mf)                                       \
        af_[mf] = *(const bf16x8*)(ap_ + 4096 + mf * 1024);                \
      __builtin_amdgcn_s_setprio(1);                                       \
      _Pragma("unroll")                                                    \
      for (int nf = 0; nf < 4; ++nf)                                       \
        _Pragma("unroll")                                                  \
        for (int mf = 0; mf < 4; ++mf)                                     \
          acc[mf][nf] = __builtin_amdgcn_mfma_f32_16x16x32_bf16(           \
              af_[mf], bfB_[nf], acc[mf][nf], 0, 0, 0);                    \
      __builtin_amdgcn_s_setprio(0);                                       \
    }                                                                      \
    bp0_ += 65536; bp1_ += 65536; ap_ += 8192;                             \
  }                                                                        \
} while (0)

__global__ __launch_bounds__(1024) void main_kernel(
    const float* __restrict__ routed, const float* __restrict__ delta,
    const float* __restrict__ simrow, const ushort* __restrict__ Bmain,
    const float* __restrict__ tpart, const float* __restrict__ gamma,
    const float* __restrict__ beta, float* __restrict__ out_arg,
    ushort* __restrict__ argb) {
  extern __shared__ char smem[];
  float* ldsW = (float*)(smem + 131072);
  float* lnS = (float*)smem;
  float* lnQ = (float*)(smem + 4096);

  int tid = threadIdx.x, l = tid & 63, wid = tid >> 6;   // wid 0..15
  int bx = blockIdx.x;                  // tokens bx*4 .. bx*4+3
  int lr = l & 15, lh = l >> 4;

  if (tid < 4) {                        // softmax over K=16 for token bx*4+tid
    int n = bx * 4 + tid;
    float sv[16], mx = -1e30f;
#pragma unroll
    for (int j = 0; j < 16; ++j) { sv[j] = simrow[n * 16 + j]; mx = fmaxf(mx, sv[j]); }
    float s = 0.f;
#pragma unroll
    for (int j = 0; j < 16; ++j) { sv[j] = expf(sv[j] - mx); s += sv[j]; }
    float inv = 1.0f / s;
#pragma unroll
    for (int j = 0; j < 16; ++j) ldsW[tid * 16 + j] = sv[j] * inv;
  }

  const int arow = tid >> 4;            // 0..63
  const int acol = tid & 15;            // 0..15

  const unsigned aoff0 = swz((unsigned)(lr * 64 + lh * 16));
  const char* abase = smem + aoff0;

  const size_t boff = (size_t)(wid >> 1) * 4096 + (size_t)(wid & 1) * 2048 +
                      (size_t)l * 8;

  f32x4 acc[4][4] = {};

  STAGE_HALF(routed);
  __syncthreads();
  HALF_LOOP(0);
  __syncthreads();
  STAGE_HALF(delta);
  __syncthreads();
  HALF_LOOP(32);
  __syncthreads();

  // ---- fused epilogue (green R16-R22; fast GELU, tpart NT) ----
  const float inv_d = 1.0f / 1024.0f;
  float gam[4], bet[4];
#pragma unroll
  for (int nf = 0; nf < 4; ++nf) {
    int c = wid * 64 + nf * 16 + lr;
    gam[nf] = gamma[c]; bet[nf] = beta[c];
  }
#pragma unroll
  for (int mf = 0; mf < 4; ++mf) {
    int tokrow = bx * 4 + mf;
    float s[4] = {0, 0, 0, 0}, q[4] = {0, 0, 0, 0};
#pragma unroll
    for (int nf = 0; nf < 4; ++nf) {
      float tp = __builtin_nontemporal_load(
          tpart + (size_t)tokrow * 1024 + wid * 64 + nf * 16 + lr);
#pragma unroll
      for (int j = 0; j < 4; ++j) {
        float h = acc[mf][nf][j] + tp;
        float u = h * (1.5957691f + 0.07135481f * h * h);
        float g = h / (1.0f + __expf(-u));
        acc[mf][nf][j] = g;
        s[j] += g; q[j] += g * g;
      }
    }
#pragma unroll
    for (int j = 0; j < 4; ++j) {
#pragma unroll
      for (int d = 1; d <= 8; d <<= 1) {
        s[j] += __shfl_xor(s[j], d, 64);
        q[j] += __shfl_xor(q[j], d, 64);
      }
    }
    if (lr == 0) {
#pragma unroll
      for (int j = 0; j < 4; ++j) {
        int row = mf * 16 + lh * 4 + j;
        lnS[row * 16 + wid] = s[j];
        lnQ[row * 16 + wid] = q[j];
      }
    }
  }
  __syncthreads();
#pragma unroll
  for (int mf = 0; mf < 4; ++mf) {
    float mu[4], rs[4], wk[4];
#pragma unroll
    for (int j = 0; j < 4; ++j) {
      int row = mf * 16 + lh * 4 + j;
      float S = 0.f, Q = 0.f;
#pragma unroll
      for (int w4 = 0; w4 < 4; ++w4) {
        f32x4 vs = *(const f32x4*)&lnS[row * 16 + w4 * 4];
        f32x4 vq = *(const f32x4*)&lnQ[row * 16 + w4 * 4];
        S += vs[0] + vs[1] + vs[2] + vs[3];
        Q += vq[0] + vq[1] + vq[2] + vq[3];
      }
      float m_ = S * inv_d;
      mu[j] = m_;
      rs[j] = rsqrtf(Q * inv_d - m_ * m_ + 1e-5f);
      wk[j] = ldsW[row];
    }
#pragma unroll
    for (int nf = 0; nf < 4; ++nf) {
      float ws = 0.f;
#pragma unroll
      for (int j = 0; j < 4; ++j) {
        float y = (acc[mf][nf][j] - mu[j]) * rs[j] * gam[nf] + bet[nf];
        ws += wk[j] * y;
      }
      ws += __shfl_xor(ws, 16, 64);
      ws += __shfl_xor(ws, 32, 64);
      if (lh == 0) {
        size_t oidx = (size_t)(bx * 4 + mf) * 1024 + wid * 64 + nf * 16 + lr;
        __builtin_nontemporal_store(ws, &out_arg[oidx]);   // never re-read
        argb[oidx] = f2bf(ws);                             // re-read 8x: cached
      }
    }
  }
}

// ---------------------------------------------------------------------------
extern "C" void kernel_launch(void* const* d_in, const int* in_sizes, int n_in,
                              void* d_out, int out_size, void* d_ws, size_t ws_size,
                              hipStream_t stream) {
  const float* token  = (const float*)d_in[0];
  const float* routed = (const float*)d_in[1];
  const float* simrow = (const float*)d_in[2];
  const float* delta  = (const float*)d_in[3];
  const float* Wl     = (const float*)d_in[4];
  const float* bl     = (const float*)d_in[5];
  const float* gamma  = (const float*)d_in[6];
  const float* beta   = (const float*)d_in[7];
  const float* Wg     = (const float*)d_in[8];
  const float* bg     = (const float*)d_in[9];

  char* ws = (char*)d_ws;
  ushort* Bmain  = (ushort*)(ws);                        // 4 MB
  ushort* Bk1    = (ushort*)(ws + (4u << 20));           // 2 MB
  ushort* Bgate  = (ushort*)(ws + (6u << 20));           // 4 MB
  float*  tpart  = (float*)(ws + (10u << 20));           // 16 MB
  ushort* tokenb = (ushort*)(ws + (26u << 20));          // 8 MB
  ushort* argb   = (ushort*)(ws + (34u << 20));          // 8 MB (total 42 MB)

  float* out_arg  = (float*)d_out;
  float* out_gate = out_arg + (size_t)4096 * 1024;

  const int SMEM = 131328;   // 32 A tiles 128K | ldsW 256B
  hipFuncSetAttribute(reinterpret_cast<const void*>(main_kernel),
                      hipFuncAttributeMaxDynamicSharedMemorySize, SMEM);

  prep_kernel<<<1536, 256, 0, stream>>>(Wl, Wg, token, Bmain, Bk1, Bgate, tokenb);
  gemm_small_b<32, 32, 0><<<dim3(64, 8), 256, 0, stream>>>(
      tokenb, tokenb, Bk1, bl, tpart);
  main_kernel<<<1024, 1024, SMEM, stream>>>(
      routed, delta, simrow, Bmain, tpart, gamma, beta, out_arg, argb);
  gemm_small_b<64, 32, 1><<<dim3(64, 8), 256, 0, stream>>>(
      tokenb, argb, Bgate, bg, out_gate);
}